// Round 3
// baseline (729.400 us; speedup 1.0000x reference)
//
#include <hip/hip_runtime.h>
#include <math.h>

#define DI __device__ __forceinline__

constexpr int B_ = 8, C_ = 64, H_ = 62, T_ = 400, S_ = 32;
constexpr int HT   = H_ * T_;      // 24800
constexpr int CHT  = C_ * HT;      // 1587200
constexpr int NPOS = B_ * HT;      // 198400
constexpr int NTOT = B_ * CHT;     // 12697600

DI float sigmoidf_(float x) { return 1.f / (1.f + expf(-x)); }
DI float gelu_(float x) { return 0.5f * x * (1.f + erff(x * 0.70710678118654752f)); }

template<int ACT> DI float act_(float v) {
  if (ACT == 1) return fmaxf(v, 0.f);
  if (ACT == 2) return sigmoidf_(v);
  return v;
}

// ---------- pointwise 64x64 conv (+bn+act) ----------
// tile: 256 positions x 64 outputs per block; 256 threads, 8 pos x 8 out each.
// REV: load input t-reversed.  SPAT: fused channel mean/max epilogue.
// DW13: input = dwconv1x3( b1*b1*ac ) computed on the fly during staging.
template<int ACT, bool REV, bool SPAT, bool DW13>
__global__ __launch_bounds__(256) void pwk(const float* __restrict__ in,
    const float* __restrict__ w, const float* __restrict__ g,
    const float* __restrict__ bb, const float* __restrict__ ac,
    const float* __restrict__ w3, float* __restrict__ out,
    float* __restrict__ comb) {
  __shared__ float ws_[64 * 64];   // ws_[c*64+o]
  __shared__ float xs[64 * 256];   // xs[c*256+p]
  const int tid = threadIdx.x;
  const int p0 = blockIdx.x * 256;
  #pragma unroll
  for (int i = 0; i < 4; ++i) {
    int idx = i * 256 + tid;            // 1024 weight quads
    int o = idx >> 4, cq = idx & 15;
    float4 wv = *(const float4*)&w[o * 64 + cq * 4];
    ws_[(cq * 4 + 0) * 64 + o] = wv.x; ws_[(cq * 4 + 1) * 64 + o] = wv.y;
    ws_[(cq * 4 + 2) * 64 + o] = wv.z; ws_[(cq * 4 + 3) * 64 + o] = wv.w;
  }
  #pragma unroll 2
  for (int i = 0; i < 16; ++i) {
    int idx = i * 256 + tid;            // 16384 input quads
    int c = idx >> 6, qq = idx & 63;
    int p = p0 + qq * 4;
    int b = p / HT, ht = p - b * HT;
    int row = ht / T_, t0 = ht - row * T_;
    float4 v;
    if (DW13) {
      const float* rp = in + b * CHT + c * HT + row * T_;
      float win[12];
      if (t0 >= 4 && t0 <= 392) {
        *(float4*)&win[0] = *(const float4*)&rp[t0 - 4];
        *(float4*)&win[4] = *(const float4*)&rp[t0];
        *(float4*)&win[8] = *(const float4*)&rp[t0 + 4];
      } else {
        #pragma unroll
        for (int k = 0; k < 12; ++k) {
          int tt = t0 - 4 + k;
          win[k] = (tt >= 0 && tt < T_) ? rp[tt] : 0.f;
        }
      }
      float acv = ac[b * 64 + c];
      #pragma unroll
      for (int k = 0; k < 12; ++k) { float f = win[k]; win[k] = f * f * acv; }
      float c0 = w3[c * 3 + 0], c1 = w3[c * 3 + 1], c2 = w3[c * 3 + 2];
      v.x = c0 * win[3] + c1 * win[4] + c2 * win[5];
      v.y = c0 * win[4] + c1 * win[5] + c2 * win[6];
      v.z = c0 * win[5] + c1 * win[6] + c2 * win[7];
      v.w = c0 * win[6] + c1 * win[7] + c2 * win[8];
    } else if (REV) {
      float4 u = *(const float4*)&in[b * CHT + c * HT + row * T_ + (T_ - 4 - t0)];
      v = make_float4(u.w, u.z, u.y, u.x);
    } else {
      v = *(const float4*)&in[b * CHT + c * HT + ht];
    }
    *(float4*)&xs[c * 256 + qq * 4] = v;
  }
  __syncthreads();
  const int og = tid & 7, pg = tid >> 3;
  const int o0 = og * 8, pp0 = pg * 8;
  float acc[8][8] = {};
  #pragma unroll 2
  for (int c = 0; c < 64; ++c) {
    float4 w0 = *(const float4*)&ws_[c * 64 + o0];
    float4 w1 = *(const float4*)&ws_[c * 64 + o0 + 4];
    float4 x0 = *(const float4*)&xs[c * 256 + pp0];
    float4 x1 = *(const float4*)&xs[c * 256 + pp0 + 4];
    float wa[8] = {w0.x, w0.y, w0.z, w0.w, w1.x, w1.y, w1.z, w1.w};
    float xa[8] = {x0.x, x0.y, x0.z, x0.w, x1.x, x1.y, x1.z, x1.w};
    #pragma unroll
    for (int oo = 0; oo < 8; ++oo)
      #pragma unroll
      for (int j = 0; j < 8; ++j)
        acc[oo][j] += wa[oo] * xa[j];
  }
  float ps[8], pm[8];
  if (SPAT) {
    #pragma unroll
    for (int j = 0; j < 8; ++j) { ps[j] = 0.f; pm[j] = -3.4e38f; }
  }
  #pragma unroll
  for (int oo = 0; oo < 8; ++oo) {
    int o = o0 + oo;
    float gv = g ? g[o] : 1.f;
    float bv = bb ? bb[o] : 0.f;
    #pragma unroll
    for (int pj = 0; pj < 8; pj += 4) {
      int p = p0 + pp0 + pj;
      int b = p / HT, ht = p - b * HT;
      float4 r;
      r.x = act_<ACT>(acc[oo][pj + 0] * gv + bv);
      r.y = act_<ACT>(acc[oo][pj + 1] * gv + bv);
      r.z = act_<ACT>(acc[oo][pj + 2] * gv + bv);
      r.w = act_<ACT>(acc[oo][pj + 3] * gv + bv);
      *(float4*)&out[b * CHT + o * HT + ht] = r;
      if (SPAT) {
        ps[pj + 0] += r.x; ps[pj + 1] += r.y; ps[pj + 2] += r.z; ps[pj + 3] += r.w;
        pm[pj + 0] = fmaxf(pm[pj + 0], r.x); pm[pj + 1] = fmaxf(pm[pj + 1], r.y);
        pm[pj + 2] = fmaxf(pm[pj + 2], r.z); pm[pj + 3] = fmaxf(pm[pj + 3], r.w);
      }
    }
  }
  if (SPAT) {
    __syncthreads();
    float* red_s = ws_;          // [8][256]
    float* red_m = xs;           // [8][256]
    #pragma unroll
    for (int j = 0; j < 8; ++j) {
      red_s[og * 256 + pp0 + j] = ps[j];
      red_m[og * 256 + pp0 + j] = pm[j];
    }
    __syncthreads();
    int p = p0 + tid;
    int b = p / HT, ht = p - b * HT;
    float s = 0.f, m = -3.4e38f;
    #pragma unroll
    for (int o8 = 0; o8 < 8; ++o8) {
      s += red_s[o8 * 256 + tid];
      m = fmaxf(m, red_m[o8 * 256 + tid]);
    }
    comb[b * 2 * HT + ht] = s * (1.f / 64.f);
    comb[b * 2 * HT + HT + ht] = m;
  }
}

// ---------- 5x5 depthwise conv, pad 2 ----------
__global__ __launch_bounds__(256) void dw5(const float* __restrict__ in,
    const float* __restrict__ w, float* __restrict__ out) {
  const int bc = blockIdx.y;
  const int c = bc & 63;
  float wg[25];
  #pragma unroll
  for (int k = 0; k < 25; ++k) wg[k] = w[c * 25 + k];
  int task = blockIdx.x * 256 + threadIdx.x;
  if (task >= 6200) return;                // 62 rows * 100 quads
  int h = task / 100;
  int t0 = (task - h * 100) << 2;
  const float* base = in + bc * HT;
  float win[5][12];
  const bool fast = (t0 >= 4) && (t0 <= 392);
  #pragma unroll
  for (int u = 0; u < 5; ++u) {
    int hh = h + u - 2;
    if (hh >= 0 && hh < H_) {
      const float* row = base + hh * T_;
      if (fast) {
        #pragma unroll
        for (int j = 0; j < 3; ++j)
          *(float4*)&win[u][4 * j] = *(const float4*)&row[t0 - 4 + 4 * j];
      } else {
        #pragma unroll
        for (int k = 0; k < 12; ++k) {
          int tt = t0 - 4 + k;
          win[u][k] = (tt >= 0 && tt < T_) ? row[tt] : 0.f;
        }
      }
    } else {
      #pragma unroll
      for (int k = 0; k < 12; ++k) win[u][k] = 0.f;
    }
  }
  float o[4] = {0.f, 0.f, 0.f, 0.f};
  #pragma unroll
  for (int u = 0; u < 5; ++u)
    #pragma unroll
    for (int v = 0; v < 5; ++v) {
      float wv = wg[u * 5 + v];
      #pragma unroll
      for (int j = 0; j < 4; ++j) o[j] += wv * win[u][j + v + 2];
    }
  *(float4*)&out[bc * HT + h * T_ + t0] = make_float4(o[0], o[1], o[2], o[3]);
}

// ---------- channel attention: raw-sum+max over half a (H,T) plane ----------
__global__ __launch_bounds__(256) void chanred(const float* __restrict__ in,
    float* __restrict__ sum_, float* __restrict__ max_) {
  int bc = blockIdx.x >> 1, hf = blockIdx.x & 1;
  const float* base = in + (size_t)bc * HT + hf * (HT / 2);
  float s = 0.f, m = -3.4e38f;
  for (int i = threadIdx.x; i < HT / 2; i += 256) {
    float v = base[i];
    s += v; m = fmaxf(m, v);
  }
  #pragma unroll
  for (int off = 32; off > 0; off >>= 1) {
    s += __shfl_down(s, off);
    m = fmaxf(m, __shfl_down(m, off));
  }
  __shared__ float ss[4], sm[4];
  int wv = threadIdx.x >> 6;
  if ((threadIdx.x & 63) == 0) { ss[wv] = s; sm[wv] = m; }
  __syncthreads();
  if (threadIdx.x == 0) {
    float S = ss[0] + ss[1] + ss[2] + ss[3];
    float M = fmaxf(fmaxf(sm[0], sm[1]), fmaxf(sm[2], sm[3]));
    sum_[hf * 512 + bc] = S;
    max_[hf * 512 + bc] = M;
  }
}

// ---------- channel attention FC: ac[b,c] = sigmoid(fc(avg)+fc(max)) ----------
__global__ __launch_bounds__(512) void cafc(const float* __restrict__ cs,
    const float* __restrict__ cm, const float* __restrict__ w1,
    const float* __restrict__ w2, float* __restrict__ ac) {
  __shared__ float sa[512], sx[512], hsum[8][4];
  int tid = threadIdx.x;
  sa[tid] = (cs[tid] + cs[512 + tid]) * (1.f / HT);
  sx[tid] = fmaxf(cm[tid], cm[512 + tid]);
  __syncthreads();
  if (tid < 32) {
    int b = tid >> 2, m = tid & 3;
    float s1 = 0.f, s2 = 0.f;
    #pragma unroll
    for (int cc = 0; cc < 64; ++cc) {
      float wv = w1[m * 64 + cc];
      s1 += sa[b * 64 + cc] * wv;
      s2 += sx[b * 64 + cc] * wv;
    }
    hsum[b][m] = fmaxf(s1, 0.f) + fmaxf(s2, 0.f);
  }
  __syncthreads();
  int b = tid >> 6, cc = tid & 63;
  float f = 0.f;
  #pragma unroll
  for (int m = 0; m < 4; ++m) f += hsum[b][m] * w2[cc * 4 + m];
  ac[tid] = sigmoidf_(f);
}

// ---------- 7x7 conv over 2 channels + sigmoid (LDS row-pair tile) ----------
__global__ __launch_bounds__(256) void conv7(const float* __restrict__ comb,
    const float* __restrict__ w, float* __restrict__ as_) {
  __shared__ float sm[2][8][408];
  __shared__ float sw[98];
  const int b = blockIdx.x / 31, hp = blockIdx.x % 31;
  const int h0 = hp * 2;
  const float* cb0 = comb + b * 2 * HT;
  const int tid = threadIdx.x;
  if (tid < 98) sw[tid] = w[tid];
  for (int e = tid; e < 2 * 8 * 408; e += 256) {
    int ci = e / 3264, rem = e - ci * 3264;
    int r = rem / 408, tt = rem - r * 408;
    int hh = h0 - 3 + r, t = tt - 4;
    float v = 0.f;
    if (hh >= 0 && hh < H_ && t >= 0 && t < T_) v = cb0[ci * HT + hh * T_ + t];
    sm[ci][r][tt] = v;
  }
  __syncthreads();
  for (int o = tid; o < 800; o += 256) {
    int oh = o / 400, ot = o - oh * 400;
    float acc = 0.f;
    #pragma unroll
    for (int ci = 0; ci < 2; ++ci)
      #pragma unroll
      for (int u = 0; u < 7; ++u)
        #pragma unroll
        for (int v = 0; v < 7; ++v)
          acc += sw[ci * 49 + u * 7 + v] * sm[ci][oh + u][ot + v + 1];
    as_[b * HT + (h0 + oh) * T_ + ot] = sigmoidf_(acc);
  }
}

// ---------- SSM ct table: ct[half][t][c2] = s_{t+1} @ Cm, via log-doubling ----------
// padded to stride 33 -> conflict-free column accesses
__global__ __launch_bounds__(256) void ssmct(const float* __restrict__ A_,
    const float* __restrict__ B_v, const float* __restrict__ Cm_,
    float* __restrict__ ct) {
  const int hf = blockIdx.y;
  const float* A = A_ + hf * S_ * S_;
  const float* Bv = B_v + hf * S_;
  const float* Cm = Cm_ + hf * S_ * C_;
  __shared__ float P[9][32][33];   // P[i] = A^(2^i)
  __shared__ float q[9][32];       // q[i] = s_(2^i)
  __shared__ float Sa[80][33], Sb[80][33];
  const int tid = threadIdx.x;
  for (int e = tid; e < 1024; e += 256) P[0][e >> 5][e & 31] = A[e];
  if (tid < 32) q[0][tid] = Bv[tid];
  __syncthreads();
  for (int i = 1; i < 9; ++i) {
    for (int e = tid; e < 1024; e += 256) {
      int r = e >> 5, cc = e & 31;
      float s = 0.f;
      #pragma unroll
      for (int k = 0; k < 32; ++k) s += P[i - 1][r][k] * P[i - 1][k][cc];
      P[i][r][cc] = s;
    }
    if (tid < 32) {
      float s = q[i - 1][tid];
      #pragma unroll
      for (int k = 0; k < 32; ++k) s += P[i - 1][tid][k] * q[i - 1][k];
      q[i][tid] = s;
    }
    __syncthreads();
  }
  const int tbase = blockIdx.x * 80;
  for (int e = tid; e < 80 * 32; e += 256) Sa[e >> 5][e & 31] = 0.f;
  __syncthreads();
  int cur = 0;
  for (int i = 0; i < 9; ++i) {
    for (int e = tid; e < 80 * 32; e += 256) {
      int tau = e >> 5, j = e & 31;
      int n = tbase + tau + 1;           // need s_n, n in [1,400]
      float v;
      if ((n >> i) & 1) {
        float s = q[i][j];
        #pragma unroll
        for (int k = 0; k < 32; ++k)
          s += P[i][j][k] * (cur ? Sb[tau][k] : Sa[tau][k]);
        v = s;
      } else {
        v = cur ? Sb[tau][j] : Sa[tau][j];
      }
      if (cur) Sa[tau][j] = v; else Sb[tau][j] = v;
    }
    cur ^= 1;
    __syncthreads();
  }
  for (int e = tid; e < 80 * 64; e += 256) {
    int tau = e >> 6, c = e & 63;
    float s = 0.f;
    #pragma unroll
    for (int k = 0; k < 32; ++k)
      s += (cur ? Sb[tau][k] : Sa[tau][k]) * Cm[k * 64 + c];
    ct[(hf * T_ + tbase + tau) * C_ + c] = s;
  }
}

// ---------- fused SSM pointwise + residual + LayerNorm(channel) + spatial gate ----
// 3100 blocks x 256 thr; block = 64 positions x 4 channel-groups of 16
__global__ __launch_bounds__(256) void k8(const float* __restrict__ cb,
    const float* __restrict__ b2, const float* __restrict__ as_,
    const float* __restrict__ ct, const float* __restrict__ D,
    const float* __restrict__ lng, const float* __restrict__ lnb,
    float* __restrict__ out, int rev) {
  __shared__ float ct_s[64 * 65];
  __shared__ float red[4 * 2 * 66];
  const int tid = threadIdx.x;
  const int pl = tid & 63, wg = tid >> 6;
  const int p0 = blockIdx.x * 64;
  #pragma unroll
  for (int k = 0; k < 16; ++k) {
    int idx = k * 256 + tid;
    int r = idx >> 6, c2 = idx & 63;
    int t = (p0 + r) % T_;
    ct_s[r * 65 + c2] = ct[t * C_ + c2];
  }
  const int p = p0 + pl;
  const int b = p / HT, ht = p - b * HT;
  const int h = ht / T_, t = ht - h * T_;
  __syncthreads();
  const float* cbp = cb + b * CHT + ht;
  const float* b2p = b2 + b * CHT + ht;
  float o[16];
  float sum = 0.f;
  #pragma unroll
  for (int i = 0; i < 16; ++i) {
    int c = wg * 16 + i;
    float xv = cbp[c * HT];
    int c2 = (62 * c + h) & 63;          // reshape(b*h, c, t) scrambling
    float u = ct_s[pl * 65 + c2] + xv * D[c2];
    float v = xv + gelu_(u);
    o[i] = v; sum += v;
  }
  red[wg * 132 + pl] = sum;
  __syncthreads();
  float S = red[0 * 132 + pl] + red[1 * 132 + pl] + red[2 * 132 + pl] + red[3 * 132 + pl];
  float mu = S * (1.f / 64.f);
  float vp = 0.f;
  #pragma unroll
  for (int i = 0; i < 16; ++i) { float d = o[i] - mu; vp += d * d; }
  red[wg * 132 + 66 + pl] = vp;
  __syncthreads();
  float Q = red[0 * 132 + 66 + pl] + red[1 * 132 + 66 + pl] +
            red[2 * 132 + 66 + pl] + red[3 * 132 + 66 + pl];
  float rstd = rsqrtf(Q * (1.f / 64.f) + 1e-5f);
  float av = as_[p];
  int htw = rev ? (h * T_ + (T_ - 1 - t)) : ht;
  float* op = out + b * CHT + htw;
  #pragma unroll
  for (int i = 0; i < 16; ++i) {
    int c = wg * 16 + i;
    float y = (o[i] - mu) * rstd * lng[c] + lnb[c];
    float bv = b2p[c * HT];
    op[c * HT] = y * sigmoidf_(bv * bv * av);
  }
}

extern "C" void kernel_launch(void* const* d_in, const int* in_sizes, int n_in,
                              void* d_out, int out_size, void* d_ws, size_t ws_size,
                              hipStream_t stream) {
  const float* x    = (const float*)d_in[0];
  const float* in_w = (const float*)d_in[1];
  const float* dwdw = (const float*)d_in[2];
  const float* dwpw = (const float*)d_in[3];
  const float* dwg  = (const float*)d_in[4];
  const float* dwb  = (const float*)d_in[5];
  const float* caw1 = (const float*)d_in[6];
  const float* caw2 = (const float*)d_in[7];
  const float* saw  = (const float*)d_in[8];
  const float* d1dw = (const float*)d_in[9];
  const float* d1pw = (const float*)d_in[10];
  const float* d1g  = (const float*)d_in[11];
  const float* d1b  = (const float*)d_in[12];
  const float* ssmA = (const float*)d_in[13];
  const float* ssmB = (const float*)d_in[14];
  const float* ssmC = (const float*)d_in[15];
  const float* ssmD = (const float*)d_in[16];
  const float* lng  = (const float*)d_in[17];
  const float* lnb  = (const float*)d_in[18];
  const float* outw = (const float*)d_in[19];
  const float* outg = (const float*)d_in[20];
  const float* outb = (const float*)d_in[21];

  size_t need = (size_t)(3 * (size_t)NTOT + 2 * NPOS + NPOS + 1024 + 1024 + 512
                         + 2 * T_ * C_) * 4;
  if (ws_size < need) return;

  float* W0 = (float*)d_ws;
  float* W1 = W0 + NTOT;
  float* W2 = W1 + NTOT;
  float* comb  = W2 + NTOT;        // B*2*HT
  float* as_   = comb + 2 * NPOS;  // B*HT
  float* casum = as_ + NPOS;       // 1024
  float* camax = casum + 1024;     // 1024
  float* ac    = camax + 1024;     // 512
  float* ct    = ac + 512;         // 2*T*C
  float* OB = (float*)d_out;       // also used as scratch (b2) mid-pipeline

  ssmct<<<dim3(5, 2), 256, 0, stream>>>(ssmA, ssmB, ssmC, ct);
  pwk<0, false, false, false><<<775, 256, 0, stream>>>(x, in_w, nullptr, nullptr,
                                                       nullptr, nullptr, W0, nullptr);

  auto run_half = [&](int hf, float* X, float* F1, float* F2) {
    const float* dw0 = dwdw + (hf * 2 + 0) * C_ * 25;
    const float* dw1 = dwdw + (hf * 2 + 1) * C_ * 25;
    const float* pw0 = dwpw + (hf * 2 + 0) * C_ * C_;
    const float* pw1 = dwpw + (hf * 2 + 1) * C_ * C_;
    const float* g0  = dwg + (hf * 2 + 0) * C_;
    const float* b0  = dwb + (hf * 2 + 0) * C_;
    const float* g1  = dwg + (hf * 2 + 1) * C_;
    const float* b1w = dwb + (hf * 2 + 1) * C_;
    dw5<<<dim3(25, 512), 256, 0, stream>>>(X, dw0, F1);
    pwk<1, false, false, false><<<775, 256, 0, stream>>>(F1, pw0, g0, b0,
                                                         nullptr, nullptr, F2, nullptr); // b1
    dw5<<<dim3(25, 512), 256, 0, stream>>>(X, dw1, F1);
    pwk<1, false, true, false><<<775, 256, 0, stream>>>(F1, pw1, g1, b1w,
                                                        nullptr, nullptr, OB, comb);     // b2+comb
    chanred<<<1024, 256, 0, stream>>>(F2, casum, camax);
    cafc<<<1, 512, 0, stream>>>(casum, camax, caw1 + hf * 4 * 64, caw2 + hf * 64 * 4, ac);
    conv7<<<248, 256, 0, stream>>>(comb, saw + hf * 98, as_);
    // dw1x3(b1^2*ac) fused into pwk load:
    pwk<2, false, false, true><<<775, 256, 0, stream>>>(F2, d1pw + hf * C_ * C_,
                                                        d1g + hf * C_, d1b + hf * C_,
                                                        ac, d1dw + hf * C_ * 3, X, nullptr);
    k8<<<3100, 256, 0, stream>>>(X, OB, as_, ct + hf * T_ * C_,
                                 ssmD + hf * C_, lng + hf * C_, lnb + hf * C_,
                                 F2, hf == 0 ? 1 : 0);
  };

  run_half(0, W0, W1, W2);     // k8 writes reversed -> W2 (= input of half 1)
  run_half(1, W2, W0, W1);     // k8 writes (reversed domain) -> W1
  // final pw reads W1 with reversed-t (undo), + bn + relu -> d_out
  pwk<1, true, false, false><<<775, 256, 0, stream>>>(W1, outw, outg, outb,
                                                      nullptr, nullptr, OB, nullptr);
}

// Round 4
// 651.379 us; speedup vs baseline: 1.1198x; 1.1198x over previous
//
#include <hip/hip_runtime.h>
#include <math.h>

#define DI __device__ __forceinline__

constexpr int B_ = 8, C_ = 64, H_ = 62, T_ = 400, S_ = 32;
constexpr int HT   = H_ * T_;      // 24800
constexpr int CHT  = C_ * HT;      // 1587200
constexpr int NPOS = B_ * HT;      // 198400
constexpr int NTOT = B_ * CHT;     // 12697600

DI float sigmoidf_(float x) { return 1.f / (1.f + expf(-x)); }
DI float gelu_(float x) { return 0.5f * x * (1.f + erff(x * 0.70710678118654752f)); }

template<int ACT> DI float act_(float v) {
  if (ACT == 1) return fmaxf(v, 0.f);
  if (ACT == 2) return sigmoidf_(v);
  return v;
}

// ---------- pointwise 64x64 conv (+bn+act) ----------
// tile: 64 positions x 64 outputs per block; 256 threads, 4x4 per thread.
// REV: load input t-reversed.  SPAT: fused channel mean/max epilogue.
// DW13: input = dwconv1x3( in*in*ac ) computed on the fly during staging.
template<int ACT, bool REV, bool SPAT, bool DW13>
__global__ __launch_bounds__(256) void pwk(const float* __restrict__ in,
    const float* __restrict__ w, const float* __restrict__ g,
    const float* __restrict__ bb, const float* __restrict__ ac,
    const float* __restrict__ w3, float* __restrict__ out,
    float* __restrict__ comb) {
  __shared__ float ws_[64 * 68];   // ws_[c*68+o]
  __shared__ float xs[64 * 68];    // xs[c*68+p]
  const int tid = threadIdx.x;
  const int p0 = blockIdx.x * 64;
  // weight staging: per wave, o = tid&63 consecutive -> conflict-free LDS writes
  #pragma unroll
  for (int i = 0; i < 4; ++i) {
    int idx = i * 256 + tid;            // 1024 weight quads
    int o = idx & 63, cq = idx >> 6;
    float4 wv = *(const float4*)&w[o * 64 + cq * 4];
    ws_[(cq * 4 + 0) * 68 + o] = wv.x; ws_[(cq * 4 + 1) * 68 + o] = wv.y;
    ws_[(cq * 4 + 2) * 68 + o] = wv.z; ws_[(cq * 4 + 3) * 68 + o] = wv.w;
  }
  #pragma unroll
  for (int i = 0; i < 4; ++i) {
    int idx = i * 256 + tid;            // 1024 input quads
    int c = idx >> 4, pq = idx & 15;
    int p = p0 + pq * 4;
    int b = p / HT, ht = p - b * HT;
    int row = ht / T_, t0 = ht - row * T_;
    float4 v;
    if (DW13) {
      const float* rp = in + b * CHT + c * HT + row * T_;
      float win[12];
      if (t0 >= 4 && t0 <= 392) {
        *(float4*)&win[0] = *(const float4*)&rp[t0 - 4];
        *(float4*)&win[4] = *(const float4*)&rp[t0];
        *(float4*)&win[8] = *(const float4*)&rp[t0 + 4];
      } else {
        #pragma unroll
        for (int k = 0; k < 12; ++k) {
          int tt = t0 - 4 + k;
          win[k] = (tt >= 0 && tt < T_) ? rp[tt] : 0.f;
        }
      }
      float acv = ac[b * 64 + c];
      #pragma unroll
      for (int k = 0; k < 12; ++k) { float f = win[k]; win[k] = f * f * acv; }
      float c0 = w3[c * 3 + 0], c1 = w3[c * 3 + 1], c2 = w3[c * 3 + 2];
      v.x = c0 * win[3] + c1 * win[4] + c2 * win[5];
      v.y = c0 * win[4] + c1 * win[5] + c2 * win[6];
      v.z = c0 * win[5] + c1 * win[6] + c2 * win[7];
      v.w = c0 * win[6] + c1 * win[7] + c2 * win[8];
    } else if (REV) {
      float4 u = *(const float4*)&in[b * CHT + c * HT + row * T_ + (T_ - 4 - t0)];
      v = make_float4(u.w, u.z, u.y, u.x);
    } else {
      v = *(const float4*)&in[b * CHT + c * HT + ht];
    }
    *(float4*)&xs[c * 68 + pq * 4] = v;
  }
  __syncthreads();
  const int p4 = (tid & 15) * 4, o4 = (tid >> 4) * 4;
  float acc[4][4] = {};
  #pragma unroll 8
  for (int c = 0; c < 64; ++c) {
    float4 wv = *(const float4*)&ws_[c * 68 + o4];
    float4 xv = *(const float4*)&xs[c * 68 + p4];
    float wa[4] = {wv.x, wv.y, wv.z, wv.w};
    float xa[4] = {xv.x, xv.y, xv.z, xv.w};
    #pragma unroll
    for (int oi = 0; oi < 4; ++oi)
      #pragma unroll
      for (int pj = 0; pj < 4; ++pj)
        acc[oi][pj] += wa[oi] * xa[pj];
  }
  int p = p0 + p4;
  int b = p / HT, ht = p - b * HT;
  float* op = out + b * CHT + ht;
  float ps[4], pm[4];
  if (SPAT) {
    #pragma unroll
    for (int j = 0; j < 4; ++j) { ps[j] = 0.f; pm[j] = -3.4e38f; }
  }
  #pragma unroll
  for (int oi = 0; oi < 4; ++oi) {
    int o = o4 + oi;
    float gv = g ? g[o] : 1.f;
    float bv = bb ? bb[o] : 0.f;
    float4 r;
    r.x = act_<ACT>(acc[oi][0] * gv + bv);
    r.y = act_<ACT>(acc[oi][1] * gv + bv);
    r.z = act_<ACT>(acc[oi][2] * gv + bv);
    r.w = act_<ACT>(acc[oi][3] * gv + bv);
    *(float4*)&op[o * HT] = r;
    if (SPAT) {
      ps[0] += r.x; ps[1] += r.y; ps[2] += r.z; ps[3] += r.w;
      pm[0] = fmaxf(pm[0], r.x); pm[1] = fmaxf(pm[1], r.y);
      pm[2] = fmaxf(pm[2], r.z); pm[3] = fmaxf(pm[3], r.w);
    }
  }
  if (SPAT) {
    __syncthreads();               // xs reads done; reuse as reduction buffer
    float* red = xs;               // [16][2][68]
    int gg = tid >> 4;
    #pragma unroll
    for (int pj = 0; pj < 4; ++pj) {
      red[gg * 136 + (p4 + pj)] = ps[pj];
      red[gg * 136 + 68 + (p4 + pj)] = pm[pj];
    }
    __syncthreads();
    if (tid < 64) {
      float s = 0.f, m = -3.4e38f;
      #pragma unroll
      for (int g2 = 0; g2 < 16; ++g2) {
        s += red[g2 * 136 + tid];
        m = fmaxf(m, red[g2 * 136 + 68 + tid]);
      }
      int pp = p0 + tid;
      int b2i = pp / HT, ht2 = pp - b2i * HT;
      comb[b2i * 2 * HT + ht2] = s * (1.f / 64.f);
      comb[b2i * 2 * HT + HT + ht2] = m;
    }
  }
}

// ---------- 5x5 depthwise conv, pad 2 ----------
__global__ __launch_bounds__(256) void dw5(const float* __restrict__ in,
    const float* __restrict__ w, float* __restrict__ out) {
  const int bc = blockIdx.y;
  const int c = bc & 63;
  float wg[25];
  #pragma unroll
  for (int k = 0; k < 25; ++k) wg[k] = w[c * 25 + k];
  int task = blockIdx.x * 256 + threadIdx.x;
  if (task >= 6200) return;                // 62 rows * 100 quads
  int h = task / 100;
  int t0 = (task - h * 100) << 2;
  const float* base = in + bc * HT;
  float win[5][12];
  const bool fast = (t0 >= 4) && (t0 <= 392);
  #pragma unroll
  for (int u = 0; u < 5; ++u) {
    int hh = h + u - 2;
    if (hh >= 0 && hh < H_) {
      const float* row = base + hh * T_;
      if (fast) {
        #pragma unroll
        for (int j = 0; j < 3; ++j)
          *(float4*)&win[u][4 * j] = *(const float4*)&row[t0 - 4 + 4 * j];
      } else {
        #pragma unroll
        for (int k = 0; k < 12; ++k) {
          int tt = t0 - 4 + k;
          win[u][k] = (tt >= 0 && tt < T_) ? row[tt] : 0.f;
        }
      }
    } else {
      #pragma unroll
      for (int k = 0; k < 12; ++k) win[u][k] = 0.f;
    }
  }
  float o[4] = {0.f, 0.f, 0.f, 0.f};
  #pragma unroll
  for (int u = 0; u < 5; ++u)
    #pragma unroll
    for (int v = 0; v < 5; ++v) {
      float wv = wg[u * 5 + v];
      #pragma unroll
      for (int j = 0; j < 4; ++j) o[j] += wv * win[u][j + v + 2];
    }
  *(float4*)&out[bc * HT + h * T_ + t0] = make_float4(o[0], o[1], o[2], o[3]);
}

// ---------- channel attention: raw-sum+max over half a (H,T) plane ----------
__global__ __launch_bounds__(256) void chanred(const float* __restrict__ in,
    float* __restrict__ sum_, float* __restrict__ max_) {
  int bc = blockIdx.x >> 1, hf = blockIdx.x & 1;
  const float* base = in + (size_t)bc * HT + hf * (HT / 2);
  float s = 0.f, m = -3.4e38f;
  for (int i = threadIdx.x; i < HT / 2; i += 256) {
    float v = base[i];
    s += v; m = fmaxf(m, v);
  }
  #pragma unroll
  for (int off = 32; off > 0; off >>= 1) {
    s += __shfl_down(s, off);
    m = fmaxf(m, __shfl_down(m, off));
  }
  __shared__ float ss[4], sm[4];
  int wv = threadIdx.x >> 6;
  if ((threadIdx.x & 63) == 0) { ss[wv] = s; sm[wv] = m; }
  __syncthreads();
  if (threadIdx.x == 0) {
    float S = ss[0] + ss[1] + ss[2] + ss[3];
    float M = fmaxf(fmaxf(sm[0], sm[1]), fmaxf(sm[2], sm[3]));
    sum_[hf * 512 + bc] = S;
    max_[hf * 512 + bc] = M;
  }
}

// ---------- channel attention FC: ac[b,c] = sigmoid(fc(avg)+fc(max)) ----------
__global__ __launch_bounds__(512) void cafc(const float* __restrict__ cs,
    const float* __restrict__ cm, const float* __restrict__ w1,
    const float* __restrict__ w2, float* __restrict__ ac) {
  __shared__ float sa[512], sx[512], hsum[8][4];
  int tid = threadIdx.x;
  sa[tid] = (cs[tid] + cs[512 + tid]) * (1.f / HT);
  sx[tid] = fmaxf(cm[tid], cm[512 + tid]);
  __syncthreads();
  if (tid < 32) {
    int b = tid >> 2, m = tid & 3;
    float s1 = 0.f, s2 = 0.f;
    #pragma unroll
    for (int cc = 0; cc < 64; ++cc) {
      float wv = w1[m * 64 + cc];
      s1 += sa[b * 64 + cc] * wv;
      s2 += sx[b * 64 + cc] * wv;
    }
    hsum[b][m] = fmaxf(s1, 0.f) + fmaxf(s2, 0.f);
  }
  __syncthreads();
  int b = tid >> 6, cc = tid & 63;
  float f = 0.f;
  #pragma unroll
  for (int m = 0; m < 4; ++m) f += hsum[b][m] * w2[cc * 4 + m];
  ac[tid] = sigmoidf_(f);
}

// ---------- 7x7 conv over 2 channels + sigmoid (LDS row-pair tile) ----------
__global__ __launch_bounds__(256) void conv7(const float* __restrict__ comb,
    const float* __restrict__ w, float* __restrict__ as_) {
  __shared__ float sm[2][8][408];
  __shared__ float sw[98];
  const int b = blockIdx.x / 31, hp = blockIdx.x % 31;
  const int h0 = hp * 2;
  const float* cb0 = comb + b * 2 * HT;
  const int tid = threadIdx.x;
  if (tid < 98) sw[tid] = w[tid];
  for (int e = tid; e < 2 * 8 * 408; e += 256) {
    int ci = e / 3264, rem = e - ci * 3264;
    int r = rem / 408, tt = rem - r * 408;
    int hh = h0 - 3 + r, t = tt - 4;
    float v = 0.f;
    if (hh >= 0 && hh < H_ && t >= 0 && t < T_) v = cb0[ci * HT + hh * T_ + t];
    sm[ci][r][tt] = v;
  }
  __syncthreads();
  for (int o = tid; o < 800; o += 256) {
    int oh = o / 400, ot = o - oh * 400;
    float acc = 0.f;
    #pragma unroll
    for (int ci = 0; ci < 2; ++ci)
      #pragma unroll
      for (int u = 0; u < 7; ++u)
        #pragma unroll
        for (int v = 0; v < 7; ++v)
          acc += sw[ci * 49 + u * 7 + v] * sm[ci][oh + u][ot + v + 1];
    as_[b * HT + (h0 + oh) * T_ + ot] = sigmoidf_(acc);
  }
}

// ---------- SSM ct table: ct[half][t][c2] = s_{t+1} @ Cm, via log-doubling ----------
// padded to stride 33 -> conflict-free column accesses
__global__ __launch_bounds__(256) void ssmct(const float* __restrict__ A_,
    const float* __restrict__ B_v, const float* __restrict__ Cm_,
    float* __restrict__ ct) {
  const int hf = blockIdx.y;
  const float* A = A_ + hf * S_ * S_;
  const float* Bv = B_v + hf * S_;
  const float* Cm = Cm_ + hf * S_ * C_;
  __shared__ float P[9][32][33];   // P[i] = A^(2^i)
  __shared__ float q[9][32];       // q[i] = s_(2^i)
  __shared__ float Sa[80][33], Sb[80][33];
  const int tid = threadIdx.x;
  for (int e = tid; e < 1024; e += 256) P[0][e >> 5][e & 31] = A[e];
  if (tid < 32) q[0][tid] = Bv[tid];
  __syncthreads();
  for (int i = 1; i < 9; ++i) {
    for (int e = tid; e < 1024; e += 256) {
      int r = e >> 5, cc = e & 31;
      float s = 0.f;
      #pragma unroll
      for (int k = 0; k < 32; ++k) s += P[i - 1][r][k] * P[i - 1][k][cc];
      P[i][r][cc] = s;
    }
    if (tid < 32) {
      float s = q[i - 1][tid];
      #pragma unroll
      for (int k = 0; k < 32; ++k) s += P[i - 1][tid][k] * q[i - 1][k];
      q[i][tid] = s;
    }
    __syncthreads();
  }
  const int tbase = blockIdx.x * 80;
  for (int e = tid; e < 80 * 32; e += 256) Sa[e >> 5][e & 31] = 0.f;
  __syncthreads();
  int cur = 0;
  for (int i = 0; i < 9; ++i) {
    for (int e = tid; e < 80 * 32; e += 256) {
      int tau = e >> 5, j = e & 31;
      int n = tbase + tau + 1;           // need s_n, n in [1,400]
      float v;
      if ((n >> i) & 1) {
        float s = q[i][j];
        #pragma unroll
        for (int k = 0; k < 32; ++k)
          s += P[i][j][k] * (cur ? Sb[tau][k] : Sa[tau][k]);
        v = s;
      } else {
        v = cur ? Sb[tau][j] : Sa[tau][j];
      }
      if (cur) Sa[tau][j] = v; else Sb[tau][j] = v;
    }
    cur ^= 1;
    __syncthreads();
  }
  for (int e = tid; e < 80 * 64; e += 256) {
    int tau = e >> 6, c = e & 63;
    float s = 0.f;
    #pragma unroll
    for (int k = 0; k < 32; ++k)
      s += (cur ? Sb[tau][k] : Sa[tau][k]) * Cm[k * 64 + c];
    ct[(hf * T_ + tbase + tau) * C_ + c] = s;
  }
}

// ---------- fused SSM pointwise + residual + LayerNorm(channel) + spatial gate ----
// 3100 blocks x 256 thr; block = 64 positions x 4 channel-groups of 16
__global__ __launch_bounds__(256) void k8(const float* __restrict__ cb,
    const float* __restrict__ b2, const float* __restrict__ as_,
    const float* __restrict__ ct, const float* __restrict__ D,
    const float* __restrict__ lng, const float* __restrict__ lnb,
    float* __restrict__ out, int rev) {
  __shared__ float ct_s[64 * 65];
  __shared__ float red[4 * 2 * 66];
  const int tid = threadIdx.x;
  const int pl = tid & 63, wg = tid >> 6;
  const int p0 = blockIdx.x * 64;
  #pragma unroll
  for (int k = 0; k < 16; ++k) {
    int idx = k * 256 + tid;
    int r = idx >> 6, c2 = idx & 63;
    int t = (p0 + r) % T_;
    ct_s[r * 65 + c2] = ct[t * C_ + c2];
  }
  const int p = p0 + pl;
  const int b = p / HT, ht = p - b * HT;
  const int h = ht / T_, t = ht - h * T_;
  __syncthreads();
  const float* cbp = cb + b * CHT + ht;
  const float* b2p = b2 + b * CHT + ht;
  float o[16];
  float sum = 0.f;
  #pragma unroll
  for (int i = 0; i < 16; ++i) {
    int c = wg * 16 + i;
    float xv = cbp[c * HT];
    int c2 = (62 * c + h) & 63;          // reshape(b*h, c, t) scrambling
    float u = ct_s[pl * 65 + c2] + xv * D[c2];
    float v = xv + gelu_(u);
    o[i] = v; sum += v;
  }
  red[wg * 132 + pl] = sum;
  __syncthreads();
  float S = red[0 * 132 + pl] + red[1 * 132 + pl] + red[2 * 132 + pl] + red[3 * 132 + pl];
  float mu = S * (1.f / 64.f);
  float vp = 0.f;
  #pragma unroll
  for (int i = 0; i < 16; ++i) { float d = o[i] - mu; vp += d * d; }
  red[wg * 132 + 66 + pl] = vp;
  __syncthreads();
  float Q = red[0 * 132 + 66 + pl] + red[1 * 132 + 66 + pl] +
            red[2 * 132 + 66 + pl] + red[3 * 132 + 66 + pl];
  float rstd = rsqrtf(Q * (1.f / 64.f) + 1e-5f);
  float av = as_[p];
  int htw = rev ? (h * T_ + (T_ - 1 - t)) : ht;
  float* op = out + b * CHT + htw;
  #pragma unroll
  for (int i = 0; i < 16; ++i) {
    int c = wg * 16 + i;
    float y = (o[i] - mu) * rstd * lng[c] + lnb[c];
    float bv = b2p[c * HT];
    op[c * HT] = y * sigmoidf_(bv * bv * av);
  }
}

extern "C" void kernel_launch(void* const* d_in, const int* in_sizes, int n_in,
                              void* d_out, int out_size, void* d_ws, size_t ws_size,
                              hipStream_t stream) {
  const float* x    = (const float*)d_in[0];
  const float* in_w = (const float*)d_in[1];
  const float* dwdw = (const float*)d_in[2];
  const float* dwpw = (const float*)d_in[3];
  const float* dwg  = (const float*)d_in[4];
  const float* dwb  = (const float*)d_in[5];
  const float* caw1 = (const float*)d_in[6];
  const float* caw2 = (const float*)d_in[7];
  const float* saw  = (const float*)d_in[8];
  const float* d1dw = (const float*)d_in[9];
  const float* d1pw = (const float*)d_in[10];
  const float* d1g  = (const float*)d_in[11];
  const float* d1b  = (const float*)d_in[12];
  const float* ssmA = (const float*)d_in[13];
  const float* ssmB = (const float*)d_in[14];
  const float* ssmC = (const float*)d_in[15];
  const float* ssmD = (const float*)d_in[16];
  const float* lng  = (const float*)d_in[17];
  const float* lnb  = (const float*)d_in[18];
  const float* outw = (const float*)d_in[19];
  const float* outg = (const float*)d_in[20];
  const float* outb = (const float*)d_in[21];

  size_t need = (size_t)(3 * (size_t)NTOT + 2 * NPOS + NPOS + 1024 + 1024 + 512
                         + 2 * T_ * C_) * 4;
  if (ws_size < need) return;

  float* W0 = (float*)d_ws;
  float* W1 = W0 + NTOT;
  float* W2 = W1 + NTOT;
  float* comb  = W2 + NTOT;        // B*2*HT
  float* as_   = comb + 2 * NPOS;  // B*HT
  float* casum = as_ + NPOS;       // 1024
  float* camax = casum + 1024;     // 1024
  float* ac    = camax + 1024;     // 512
  float* ct    = ac + 512;         // 2*T*C
  float* OB = (float*)d_out;       // also used as scratch (b2) mid-pipeline

  ssmct<<<dim3(5, 2), 256, 0, stream>>>(ssmA, ssmB, ssmC, ct);
  pwk<0, false, false, false><<<3100, 256, 0, stream>>>(x, in_w, nullptr, nullptr,
                                                        nullptr, nullptr, W0, nullptr);

  auto run_half = [&](int hf, float* X, float* F1, float* F2) {
    const float* dw0 = dwdw + (hf * 2 + 0) * C_ * 25;
    const float* dw1 = dwdw + (hf * 2 + 1) * C_ * 25;
    const float* pw0 = dwpw + (hf * 2 + 0) * C_ * C_;
    const float* pw1 = dwpw + (hf * 2 + 1) * C_ * C_;
    const float* g0  = dwg + (hf * 2 + 0) * C_;
    const float* b0  = dwb + (hf * 2 + 0) * C_;
    const float* g1  = dwg + (hf * 2 + 1) * C_;
    const float* b1w = dwb + (hf * 2 + 1) * C_;
    dw5<<<dim3(25, 512), 256, 0, stream>>>(X, dw0, F1);
    pwk<1, false, false, false><<<3100, 256, 0, stream>>>(F1, pw0, g0, b0,
                                                          nullptr, nullptr, F2, nullptr); // b1
    dw5<<<dim3(25, 512), 256, 0, stream>>>(X, dw1, F1);
    pwk<1, false, true, false><<<3100, 256, 0, stream>>>(F1, pw1, g1, b1w,
                                                         nullptr, nullptr, OB, comb);     // b2+comb
    chanred<<<1024, 256, 0, stream>>>(F2, casum, camax);
    cafc<<<1, 512, 0, stream>>>(casum, camax, caw1 + hf * 4 * 64, caw2 + hf * 64 * 4, ac);
    conv7<<<248, 256, 0, stream>>>(comb, saw + hf * 98, as_);
    // dw1x3(b1^2*ac) fused into pwk load:
    pwk<2, false, false, true><<<3100, 256, 0, stream>>>(F2, d1pw + hf * C_ * C_,
                                                         d1g + hf * C_, d1b + hf * C_,
                                                         ac, d1dw + hf * C_ * 3, X, nullptr);
    k8<<<3100, 256, 0, stream>>>(X, OB, as_, ct + hf * T_ * C_,
                                 ssmD + hf * C_, lng + hf * C_, lnb + hf * C_,
                                 F2, hf == 0 ? 1 : 0);
  };

  run_half(0, W0, W1, W2);     // k8 writes reversed -> W2 (= input of half 1)
  run_half(1, W2, W0, W1);     // k8 writes (reversed domain) -> W1
  // final pw reads W1 with reversed-t (undo), + bn + relu -> d_out
  pwk<1, true, false, false><<<3100, 256, 0, stream>>>(W1, outw, outg, outb,
                                                       nullptr, nullptr, OB, nullptr);
}